// Round 10
// baseline (134.276 us; speedup 1.0000x reference)
//
#include <hip/hip_runtime.h>

#define DEV __device__ __forceinline__

typedef __attribute__((ext_vector_type(8))) short bf16x8;
typedef __attribute__((ext_vector_type(4))) short bf16x4;
typedef __attribute__((ext_vector_type(4))) float f32x4;
typedef __attribute__((ext_vector_type(4))) unsigned int u32x4;

constexpr int Bb = 8;
constexpr int Nn = 1024;
constexpr int DIMm = 512;
constexpr int Hh = 8;
constexpr int Dh = 64;
constexpr int Mm = Bb * Nn;  // 8192
constexpr float LN10K = 9.210340371976184f;   // ln(10000)
constexpr float LOG2E = 1.4426950408889634f;  // log2(e)

DEV short f2bf(float f) {
  unsigned int u = __float_as_uint(f);
  u += 0x7fffu + ((u >> 16) & 1u);  // RNE
  return (short)(u >> 16);
}

DEV unsigned int cvtpk(float lo, float hi) {  // dword = {bf16(lo), bf16(hi)}
  unsigned int r;
  asm("v_cvt_pk_bf16_f32 %0, %1, %2" : "=v"(r) : "v"(lo), "v"(hi));
  return r;
}

DEV bf16x8 comb(bf16x4 lo, bf16x4 hi) {
  bf16x8 r;
  r[0] = lo[0]; r[1] = lo[1]; r[2] = lo[2]; r[3] = lo[3];
  r[4] = hi[0]; r[5] = hi[1]; r[6] = hi[2]; r[7] = hi[3];
  return r;
}

DEV f32x4 mfma16(bf16x8 a, bf16x8 b, f32x4 c) {
  return __builtin_amdgcn_mfma_f32_16x16x32_bf16(a, b, c, 0, 0, 0);
}

DEV void gload16(const void* g, void* l) {
  __builtin_amdgcn_global_load_lds(
      (const __attribute__((address_space(1))) void*)g,
      (__attribute__((address_space(3))) void*)l, 16, 0, 0);
}

// ---------------------------------------------------------------------------
// prep: x -> bf16 ; w_qkv -> transposed bf16 [1536][512] ; w_out -> [512][512];
// RoPE cos/sin table [N][32] float2
// ---------------------------------------------------------------------------
__global__ void prep_kernel(const float* __restrict__ x, const float* __restrict__ wq,
                            const float* __restrict__ wo, short* __restrict__ x_bf,
                            short* __restrict__ wqkvT, short* __restrict__ woutT,
                            float2* __restrict__ tab) {
  int stride = gridDim.x * blockDim.x;
  int t = blockIdx.x * blockDim.x + threadIdx.x;
  for (int i = t; i < Mm * DIMm / 4; i += stride) {
    float4 v = ((const float4*)x)[i];
    bf16x4 o;
    o[0] = f2bf(v.x); o[1] = f2bf(v.y); o[2] = f2bf(v.z); o[3] = f2bf(v.w);
    *(bf16x4*)(x_bf + (size_t)i * 4) = o;
  }
  for (int i = t; i < 1536 * 512; i += stride) {
    int n = i >> 9, k = i & 511;
    wqkvT[i] = f2bf(wq[(size_t)k * 1536 + n]);
  }
  for (int i = t; i < 512 * 512; i += stride) {
    int n = i >> 9, k = i & 511;
    woutT[i] = f2bf(wo[(size_t)k * 512 + n]);
  }
  for (int i = t; i < Nn * 32; i += stride) {
    int n = i >> 5, d2 = i & 31;
    float fr = (float)n * __expf(-(float)(2 * d2) * (LN10K / 64.f));
    float sn, cs;
    __sincosf(fr, &sn, &cs);
    tab[i] = make_float2(cs, sn);
  }
}

// ---------------------------------------------------------------------------
// bias_prep: permute pos_bias[h][i][j] (f32) into S^T-fragment order so the
// attention wave's bias load is ONE contiguous 1KB f32x4 load (was a 64-way
// row scatter). Layout:
//   out[ ((h*64 + i>>4)*16 + j>>6)*1024 + ((j>>4)&3)*256 + ((j>>2)&3)*64
//        + (i&15)*4 + (j&3) ]  = bias[h][i][j]
// Reads coalesced float4; writes 16B chunks at 256B stride (16x fewer
// transactions than the old read-side scatter, and it runs once).
// ---------------------------------------------------------------------------
__global__ void bias_prep(const float* __restrict__ pb, float* __restrict__ bias_f) {
  int stride = gridDim.x * blockDim.x;
  int t0 = blockIdx.x * blockDim.x + threadIdx.x;
  for (int idx = t0; idx < (Hh * Nn * Nn) / 4; idx += stride) {
    int idx4 = idx << 2;
    int h = idx4 >> 20;
    int i = (idx4 >> 10) & 1023;
    int j = idx4 & 1023;
    float4 v = ((const float4*)pb)[idx];
    size_t base = ((size_t)((h * 64 + (i >> 4)) * 16 + (j >> 6))) * 1024 +
                  (size_t)(((j >> 4) & 3) * 256 + ((j >> 2) & 3) * 64 + (i & 15) * 4);
    *(float4*)(bias_f + base) = v;
  }
}

// ---------------------------------------------------------------------------
// GEMM: A[Mx512] bf16 row-major, Bt[Ncols x 512] bf16 (pre-transposed).
// QKV==1: epilogue applies RoPE (table) + q-scale(0.125) and writes Q/K/V in
//   MFMA-fragment-order global layout (65536 shorts per bh):
//   Q,K (A/B-operand frag, row=n, k=d):
//     off = (n>>4)*1024 + (d>>5)*512 + ((n&15) + 16*((d&15)>>2))*8
//           + ((d&3) | ((d&16)>>2))
//   V (B-operand frag of PV, row=d, k=j):
//     off = (j>>6)*4096 + ((d>>4)*2 + ((j>>5)&1))*512
//           + ((d&15) + 16*((j&15)>>2))*8 + ((j&3) | ((j&16)>>2))
// QKV==0: plain f32 store.
// ---------------------------------------------------------------------------
template <int QKV>
__global__ __launch_bounds__(256) void gemm_k(const short* __restrict__ A,
                                              const short* __restrict__ Bt,
                                              float* __restrict__ outF,
                                              short* __restrict__ qr,
                                              short* __restrict__ kr,
                                              short* __restrict__ vt,
                                              const float2* __restrict__ tab) {
  __shared__ short Al[128][40];
  __shared__ short Bl[128][40];
  const int tid = threadIdx.x;
  const int lane = tid & 63;
  const int wid = tid >> 6;
  const int wm = wid >> 1, wn = wid & 1;
  const int li = lane & 15, g4 = (lane >> 4) << 2;
  const int m0 = blockIdx.x * 128, n0 = blockIdx.y * 128;

  f32x4 zero4 = {0.f, 0.f, 0.f, 0.f};
  f32x4 acc[4][4];
#pragma unroll
  for (int i = 0; i < 4; ++i)
#pragma unroll
    for (int j = 0; j < 4; ++j) acc[i][j] = zero4;

  for (int kt = 0; kt < 512; kt += 32) {
#pragma unroll
    for (int p = 0; p < 2; ++p) {
      int e = (tid + p * 256) * 8;
      int r = e >> 5, c = e & 31;
      *(u32x4*)(&Al[r][c]) = *(const u32x4*)(A + (size_t)(m0 + r) * 512 + kt + c);
      *(u32x4*)(&Bl[r][c]) = *(const u32x4*)(Bt + (size_t)(n0 + r) * 512 + kt + c);
    }
    __syncthreads();
    bf16x8 af[4], bfr[4];
#pragma unroll
    for (int mt = 0; mt < 4; ++mt) {
      int row = wm * 64 + mt * 16 + li;
      af[mt] = comb(*(const bf16x4*)(&Al[row][g4]), *(const bf16x4*)(&Al[row][16 + g4]));
    }
#pragma unroll
    for (int nt = 0; nt < 4; ++nt) {
      int row = wn * 64 + nt * 16 + li;
      bfr[nt] = comb(*(const bf16x4*)(&Bl[row][g4]), *(const bf16x4*)(&Bl[row][16 + g4]));
    }
#pragma unroll
    for (int mt = 0; mt < 4; ++mt)
#pragma unroll
      for (int nt = 0; nt < 4; ++nt)
        acc[mt][nt] = mfma16(af[mt], bfr[nt], acc[mt][nt]);
    __syncthreads();
  }

  if (QKV == 0) {
#pragma unroll
    for (int mt = 0; mt < 4; ++mt) {
      int mb = m0 + wm * 64 + mt * 16 + g4;
#pragma unroll
      for (int nt = 0; nt < 4; ++nt) {
        int c = n0 + wn * 64 + nt * 16 + li;
#pragma unroll
        for (int r = 0; r < 4; ++r) outF[(size_t)(mb + r) * 512 + c] = acc[mt][nt][r];
      }
    }
  } else {
    const int sec = n0 >> 9;  // 0=q 1=k 2=v
#pragma unroll
    for (int mt = 0; mt < 4; ++mt) {
      int mb = m0 + wm * 64 + mt * 16 + g4;
      int b_ = mb >> 10;
      int nb = mb & 1023;  // token index; nb ≡ g4 (mod 16)
#pragma unroll
      for (int nt = 0; nt < 4; ++nt) {
        int c = n0 + wn * 64 + nt * 16 + li;
        int cs = c & 511;
        int hh = cs >> 6, d = cs & 63;
        size_t bhoff = (size_t)(b_ * Hh + hh) * 65536;
        if (sec == 2) {
          int dt = d >> 4, liD = d & 15;
          int kkJ = (nb >> 5) & 1;
          int gj = (nb & 15) >> 2;
          int s0 = (nb & 16) >> 2;  // 0 or 4
          size_t off = bhoff + (size_t)(nb >> 6) * 4096 +
                       (size_t)((dt * 2 + kkJ) * 512) + (size_t)(liD + 16 * gj) * 8 + s0;
          uint2 st;
          st.x = cvtpk(acc[mt][nt][0], acc[mt][nt][1]);
          st.y = cvtpk(acc[mt][nt][2], acc[mt][nt][3]);
          *(uint2*)(vt + off) = st;
        } else {
          int kkD = d >> 5;
          int gd = (d & 15) >> 2;
          int sD = (d & 3) | ((d & 16) >> 2);
          size_t off = bhoff + (size_t)(nb >> 4) * 1024 + (size_t)(kkD * 512) +
                       (size_t)((nb & 15) + 16 * gd) * 8 + sD;
          short* dst = (sec == 0 ? qr : kr) + off;
#pragma unroll
          for (int r = 0; r < 4; ++r) {
            float v0 = acc[mt][nt][r];
            float vp = __shfl_xor(v0, 1, 64);  // RoPE pair partner (adjacent d)
            float2 cssn = tab[(size_t)(nb + r) * 32 + (d >> 1)];
            float rot = (d & 1) ? vp : -vp;
            float res = v0 * cssn.x + rot * cssn.y;
            if (sec == 0) res *= 0.125f;  // Dh^-0.5 (e-domain; LOG2E applied in exp)
            dst[(size_t)r * 8] = f2bf(res);
          }
        }
      }
    }
  }
}

// ---------------------------------------------------------------------------
// Flash attention v8 = v6 shell + fragment-order bias.
// 2-phase double-buffered LDS pipeline (KVBLK=64), 4 waves x 16 q-rows,
// grid = 1024 blocks (4/CU, 16 waves/CU). Bias is now read via ONE contiguous
// 1KB f32x4 wave-load per js (was 64-way row scatter = 4096 transactions per
// CU-tile; now ~1024).
// ---------------------------------------------------------------------------
constexpr int KVB = 64;
constexpr int NTT = Nn / KVB;  // 16

__global__ __launch_bounds__(256, 4) void attn_k(const short* __restrict__ qf_g,
                                                 const short* __restrict__ kf_g,
                                                 const short* __restrict__ vf_g,
                                                 const float* __restrict__ bias_f,
                                                 short* __restrict__ ao) {
  __shared__ short Kls[2][4096];  // [buf][64j x 64d frag-order], 8 KB each
  __shared__ short Vls[2][4096];  // [buf][64d x 64j frag-order], 8 KB each
  const int tid = threadIdx.x, lane = tid & 63, w = tid >> 6;
  const int li = lane & 15, g4 = (lane >> 4) << 2;
  // Block mapping: h pin to XCD, b_ fast, it slow.
  const int bid = blockIdx.x;
  const int h = bid & 7;
  const int b_ = (bid >> 3) & 7;
  const int it = bid >> 6;
  const int bh = b_ * 8 + h;
  const int i0 = it * 64;

  const short* qbase = qf_g + (size_t)bh * 65536 + (size_t)(it * 4 + w) * 1024 + lane * 8;
  bf16x8 qf0 = *(const bf16x8*)(qbase);
  bf16x8 qf1 = *(const bf16x8*)(qbase + 512);

  const short* kb = kf_g + (size_t)bh * 65536;
  const short* vb = vf_g + (size_t)bh * 65536;
  // fragment-order bias: per (h, i_blk=it*4+w): 16 jt-tiles x 1024 floats;
  // lane offset (lane>>4)*64 + li*4 makes each js-load a contiguous 1KB.
  const float* bfr = bias_f + (size_t)((h * 64 + it * 4 + w) * 16) * 1024 +
                     (size_t)((lane >> 4) * 64 + li * 4);

  float m_run = -1e30f, l_run = 0.f;
  f32x4 zero4 = {0.f, 0.f, 0.f, 0.f};
  f32x4 acc[4];
#pragma unroll
  for (int i = 0; i < 4; ++i) acc[i] = zero4;

  // ---- staging macro: 4 x gload16 per thread (K 8KB + V 8KB per tile) ----
#define STAGE_TILE(T, BUF)                                                  \
  do {                                                                      \
    const short* ks_ = kb + (size_t)(T) * 4096;                             \
    const short* vs_ = vb + (size_t)(T) * 4096;                             \
    gload16(ks_ + (size_t)tid * 8, &Kls[BUF][(size_t)(w * 64) * 8]);        \
    gload16(ks_ + (size_t)(256 + tid) * 8,                                  \
            &Kls[BUF][(size_t)(256 + w * 64) * 8]);                         \
    gload16(vs_ + (size_t)tid * 8, &Vls[BUF][(size_t)(w * 64) * 8]);        \
    gload16(vs_ + (size_t)(256 + tid) * 8,                                  \
            &Vls[BUF][(size_t)(256 + w * 64) * 8]);                         \
  } while (0)

  f32x4 bbA[4], bbB[4];

  // prologue: stage tile 0, load its bias
  STAGE_TILE(0, 0);
#pragma unroll
  for (int js = 0; js < 4; ++js) bbA[js] = *(const f32x4*)(bfr + js * 256);
  asm volatile("s_waitcnt vmcnt(0)" ::: "memory");
  __builtin_amdgcn_s_barrier();

  int cur = 0;
#pragma unroll 1
  for (int t = 0; t < NTT; ++t) {
    // phase 1: issue next tile's staging (stays in flight across compute)
    if (t + 1 < NTT) {
      STAGE_TILE(t + 1, cur ^ 1);
#pragma unroll
      for (int js = 0; js < 4; ++js)
        bbB[js] = *(const f32x4*)(bfr + (size_t)(t + 1) * 1024 + js * 256);
    }

    // phase 2: compute current tile from LDS
    const short* KB = &Kls[cur][0];
    const short* VB = &Vls[cur][0];
    f32x4 s[4];
    __builtin_amdgcn_s_setprio(1);
#pragma unroll
    for (int js = 0; js < 4; ++js) {
      bf16x8 k0 = *(const bf16x8*)(KB + js * 1024 + lane * 8);
      bf16x8 k1 = *(const bf16x8*)(KB + js * 1024 + 512 + lane * 8);
      f32x4 sa = mfma16(k0, qf0, bbA[js]);
      s[js] = mfma16(k1, qf1, sa);
    }
    __builtin_amdgcn_s_setprio(0);

    // row max
    float mx = fmaxf(fmaxf(fmaxf(s[0][0], s[0][1]), fmaxf(s[0][2], s[0][3])),
                     fmaxf(fmaxf(s[1][0], s[1][1]), fmaxf(s[1][2], s[1][3])));
    float mx2 = fmaxf(fmaxf(fmaxf(s[2][0], s[2][1]), fmaxf(s[2][2], s[2][3])),
                      fmaxf(fmaxf(s[3][0], s[3][1]), fmaxf(s[3][2], s[3][3])));
    mx = fmaxf(mx, mx2);
    mx = fmaxf(mx, __shfl_xor(mx, 16, 64));
    mx = fmaxf(mx, __shfl_xor(mx, 32, 64));

    if (!__all(mx - m_run <= 8.0f)) {  // defer-max (T13)
      float mn = fmaxf(m_run, mx);
      float sc = __builtin_amdgcn_exp2f((m_run - mn) * LOG2E);
      l_run *= sc;
      m_run = mn;
      float fs0 = __shfl(sc, g4 + 0, 64), fs1 = __shfl(sc, g4 + 1, 64);
      float fs2 = __shfl(sc, g4 + 2, 64), fs3 = __shfl(sc, g4 + 3, 64);
#pragma unroll
      for (int dt = 0; dt < 4; ++dt) {
        acc[dt][0] *= fs0; acc[dt][1] *= fs1;
        acc[dt][2] *= fs2; acc[dt][3] *= fs3;
      }
    }

    float nm = -m_run * LOG2E;
    float rs = 0.f;
#pragma unroll
    for (int js = 0; js < 4; ++js)
#pragma unroll
      for (int r = 0; r < 4; ++r) {
        float p = __builtin_amdgcn_exp2f(__builtin_fmaf(s[js][r], LOG2E, nm));
        s[js][r] = p;
        rs += p;
      }
    rs += __shfl_xor(rs, 16, 64);
    rs += __shfl_xor(rs, 32, 64);
    l_run += rs;

    // P -> bf16 A-frags: pf[kk] covers j in [32kk, 32kk+32)
    bf16x8 pf[2];
#pragma unroll
    for (int kk = 0; kk < 2; ++kk) {
      union { bf16x8 v8; unsigned int d[4]; } u;
      u.d[0] = cvtpk(s[2 * kk][0], s[2 * kk][1]);
      u.d[1] = cvtpk(s[2 * kk][2], s[2 * kk][3]);
      u.d[2] = cvtpk(s[2 * kk + 1][0], s[2 * kk + 1][1]);
      u.d[3] = cvtpk(s[2 * kk + 1][2], s[2 * kk + 1][3]);
      pf[kk] = u.v8;
    }

    // PV
    __builtin_amdgcn_s_setprio(1);
#pragma unroll
    for (int dt = 0; dt < 4; ++dt) {
      bf16x8 vf0 = *(const bf16x8*)(VB + (dt * 2 + 0) * 512 + lane * 8);
      bf16x8 vf1 = *(const bf16x8*)(VB + (dt * 2 + 1) * 512 + lane * 8);
      f32x4 a = mfma16(pf[0], vf0, acc[dt]);
      acc[dt] = mfma16(pf[1], vf1, a);
    }
    __builtin_amdgcn_s_setprio(0);

    // phase 3: next tile's staging is done by now; sync buffers
    asm volatile("s_waitcnt vmcnt(0)" ::: "memory");
    __builtin_amdgcn_s_barrier();
#pragma unroll
    for (int js = 0; js < 4; ++js) bbA[js] = bbB[js];
    cur ^= 1;
  }
#undef STAGE_TILE

  float rl = 1.f / l_run;
  float fr0 = __shfl(rl, g4 + 0, 64), fr1 = __shfl(rl, g4 + 1, 64);
  float fr2 = __shfl(rl, g4 + 2, 64), fr3 = __shfl(rl, g4 + 3, 64);
#pragma unroll
  for (int dt = 0; dt < 4; ++dt) {
    float fr[4] = {fr0, fr1, fr2, fr3};
#pragma unroll
    for (int r = 0; r < 4; ++r) {
      int i_ = i0 + w * 16 + g4 + r;
      ao[((size_t)(b_ * Nn + i_)) * 512 + h * 64 + dt * 16 + li] =
          f2bf(acc[dt][r] * fr[r]);
    }
  }
}

// ---------------------------------------------------------------------------
extern "C" void kernel_launch(void* const* d_in, const int* in_sizes, int n_in,
                              void* d_out, int out_size, void* d_ws, size_t ws_size,
                              hipStream_t stream) {
  const float* x = (const float*)d_in[0];
  const float* pb = (const float*)d_in[1];
  const float* wq = (const float*)d_in[2];
  const float* wo = (const float*)d_in[3];
  float* out = (float*)d_out;

  short* w = (short*)d_ws;
  short* x_bf = w;  w += (size_t)Mm * DIMm;      // 8 MB
  short* wqkvT = w; w += 1536 * 512;             // 1.5 MB
  short* woutT = w; w += 512 * 512;              // 0.5 MB
  short* qr = w;    w += (size_t)Mm * DIMm;      // 8 MB (frag-order)
  short* kr = w;    w += (size_t)Mm * DIMm;      // 8 MB (frag-order)
  short* vt = w;    w += (size_t)Mm * DIMm;      // 8 MB (frag-order)
  float2* tab = (float2*)w; w += Nn * 32 * 4;    // 256 KB
  float* bias_f = (float*)w; w += (size_t)Hh * Nn * Nn * 2;  // 32 MB (frag-order f32)
  short* ao = x_bf;  // x_bf dead after qkv GEMM

  prep_kernel<<<1024, 256, 0, stream>>>(x, wq, wo, x_bf, wqkvT, woutT, tab);
  bias_prep<<<2048, 256, 0, stream>>>(pb, bias_f);
  gemm_k<1><<<dim3(64, 12), 256, 0, stream>>>(x_bf, wqkvT, nullptr, qr, kr, vt, tab);
  attn_k<<<1024, 256, 0, stream>>>(qr, kr, vt, bias_f, ao);
  gemm_k<0><<<dim3(64, 4), 256, 0, stream>>>(ao, woutT, out, nullptr, nullptr, nullptr, tab);
}

// Round 11
// 123.923 us; speedup vs baseline: 1.0835x; 1.0835x over previous
//
#include <hip/hip_runtime.h>

#define DEV __device__ __forceinline__

typedef __attribute__((ext_vector_type(8))) short bf16x8;
typedef __attribute__((ext_vector_type(4))) short bf16x4;
typedef __attribute__((ext_vector_type(4))) float f32x4;
typedef __attribute__((ext_vector_type(4))) unsigned int u32x4;

constexpr int Bb = 8;
constexpr int Nn = 1024;
constexpr int DIMm = 512;
constexpr int Hh = 8;
constexpr int Dh = 64;
constexpr int Mm = Bb * Nn;  // 8192
constexpr float LN10K = 9.210340371976184f;   // ln(10000)
constexpr float LOG2E = 1.4426950408889634f;  // log2(e)

DEV short f2bf(float f) {
  unsigned int u = __float_as_uint(f);
  u += 0x7fffu + ((u >> 16) & 1u);  // RNE
  return (short)(u >> 16);
}

DEV unsigned int cvtpk(float lo, float hi) {  // dword = {bf16(lo), bf16(hi)}
  unsigned int r;
  asm("v_cvt_pk_bf16_f32 %0, %1, %2" : "=v"(r) : "v"(lo), "v"(hi));
  return r;
}

DEV bf16x8 comb(bf16x4 lo, bf16x4 hi) {
  bf16x8 r;
  r[0] = lo[0]; r[1] = lo[1]; r[2] = lo[2]; r[3] = lo[3];
  r[4] = hi[0]; r[5] = hi[1]; r[6] = hi[2]; r[7] = hi[3];
  return r;
}

DEV f32x4 mfma16(bf16x8 a, bf16x8 b, f32x4 c) {
  return __builtin_amdgcn_mfma_f32_16x16x32_bf16(a, b, c, 0, 0, 0);
}

DEV void gload16(const void* g, void* l) {
  __builtin_amdgcn_global_load_lds(
      (const __attribute__((address_space(1))) void*)g,
      (__attribute__((address_space(3))) void*)l, 16, 0, 0);
}

// ---------------------------------------------------------------------------
// prep: x -> bf16 ; w_qkv -> transposed bf16 [1536][512] ; w_out -> [512][512];
// RoPE cos/sin table [N][32] float2
// ---------------------------------------------------------------------------
__global__ void prep_kernel(const float* __restrict__ x, const float* __restrict__ wq,
                            const float* __restrict__ wo, short* __restrict__ x_bf,
                            short* __restrict__ wqkvT, short* __restrict__ woutT,
                            float2* __restrict__ tab) {
  int stride = gridDim.x * blockDim.x;
  int t = blockIdx.x * blockDim.x + threadIdx.x;
  for (int i = t; i < Mm * DIMm / 4; i += stride) {
    float4 v = ((const float4*)x)[i];
    bf16x4 o;
    o[0] = f2bf(v.x); o[1] = f2bf(v.y); o[2] = f2bf(v.z); o[3] = f2bf(v.w);
    *(bf16x4*)(x_bf + (size_t)i * 4) = o;
  }
  for (int i = t; i < 1536 * 512; i += stride) {
    int n = i >> 9, k = i & 511;
    wqkvT[i] = f2bf(wq[(size_t)k * 1536 + n]);
  }
  for (int i = t; i < 512 * 512; i += stride) {
    int n = i >> 9, k = i & 511;
    woutT[i] = f2bf(wo[(size_t)k * 512 + n]);
  }
  for (int i = t; i < Nn * 32; i += stride) {
    int n = i >> 5, d2 = i & 31;
    float fr = (float)n * __expf(-(float)(2 * d2) * (LN10K / 64.f));
    float sn, cs;
    __sincosf(fr, &sn, &cs);
    tab[i] = make_float2(cs, sn);
  }
}

// ---------------------------------------------------------------------------
// bias_cvt: pos_bias f32 -> bf16, same [h][i][j] layout. Fully coalesced both
// sides (read float4 / write 8B). Launched AFTER gemm_k<1> so the qkv GEMM's
// L2 working set (x_bf, wqkvT) is not evicted (R10 regression).
// ---------------------------------------------------------------------------
__global__ void bias_cvt(const float* __restrict__ pb, short* __restrict__ bb) {
  int stride = gridDim.x * blockDim.x;
  int t0 = blockIdx.x * blockDim.x + threadIdx.x;
  for (int i = t0; i < (Hh * Nn * Nn) / 4; i += stride) {
    float4 v = ((const float4*)pb)[i];
    uint2 st;
    st.x = cvtpk(v.x, v.y);
    st.y = cvtpk(v.z, v.w);
    *(uint2*)(bb + (size_t)i * 4) = st;
  }
}

// ---------------------------------------------------------------------------
// GEMM: A[Mx512] bf16 row-major, Bt[Ncols x 512] bf16 (pre-transposed).
// QKV==1: epilogue applies RoPE (table) + q-scale(0.125) and writes Q/K/V in
//   MFMA-fragment-order global layout (65536 shorts per bh).
// QKV==0: plain f32 store.
// ---------------------------------------------------------------------------
template <int QKV>
__global__ __launch_bounds__(256) void gemm_k(const short* __restrict__ A,
                                              const short* __restrict__ Bt,
                                              float* __restrict__ outF,
                                              short* __restrict__ qr,
                                              short* __restrict__ kr,
                                              short* __restrict__ vt,
                                              const float2* __restrict__ tab) {
  __shared__ short Al[128][40];
  __shared__ short Bl[128][40];
  const int tid = threadIdx.x;
  const int lane = tid & 63;
  const int wid = tid >> 6;
  const int wm = wid >> 1, wn = wid & 1;
  const int li = lane & 15, g4 = (lane >> 4) << 2;
  const int m0 = blockIdx.x * 128, n0 = blockIdx.y * 128;

  f32x4 zero4 = {0.f, 0.f, 0.f, 0.f};
  f32x4 acc[4][4];
#pragma unroll
  for (int i = 0; i < 4; ++i)
#pragma unroll
    for (int j = 0; j < 4; ++j) acc[i][j] = zero4;

  for (int kt = 0; kt < 512; kt += 32) {
#pragma unroll
    for (int p = 0; p < 2; ++p) {
      int e = (tid + p * 256) * 8;
      int r = e >> 5, c = e & 31;
      *(u32x4*)(&Al[r][c]) = *(const u32x4*)(A + (size_t)(m0 + r) * 512 + kt + c);
      *(u32x4*)(&Bl[r][c]) = *(const u32x4*)(Bt + (size_t)(n0 + r) * 512 + kt + c);
    }
    __syncthreads();
    bf16x8 af[4], bfr[4];
#pragma unroll
    for (int mt = 0; mt < 4; ++mt) {
      int row = wm * 64 + mt * 16 + li;
      af[mt] = comb(*(const bf16x4*)(&Al[row][g4]), *(const bf16x4*)(&Al[row][16 + g4]));
    }
#pragma unroll
    for (int nt = 0; nt < 4; ++nt) {
      int row = wn * 64 + nt * 16 + li;
      bfr[nt] = comb(*(const bf16x4*)(&Bl[row][g4]), *(const bf16x4*)(&Bl[row][16 + g4]));
    }
#pragma unroll
    for (int mt = 0; mt < 4; ++mt)
#pragma unroll
      for (int nt = 0; nt < 4; ++nt)
        acc[mt][nt] = mfma16(af[mt], bfr[nt], acc[mt][nt]);
    __syncthreads();
  }

  if (QKV == 0) {
#pragma unroll
    for (int mt = 0; mt < 4; ++mt) {
      int mb = m0 + wm * 64 + mt * 16 + g4;
#pragma unroll
      for (int nt = 0; nt < 4; ++nt) {
        int c = n0 + wn * 64 + nt * 16 + li;
#pragma unroll
        for (int r = 0; r < 4; ++r) outF[(size_t)(mb + r) * 512 + c] = acc[mt][nt][r];
      }
    }
  } else {
    const int sec = n0 >> 9;  // 0=q 1=k 2=v
#pragma unroll
    for (int mt = 0; mt < 4; ++mt) {
      int mb = m0 + wm * 64 + mt * 16 + g4;
      int b_ = mb >> 10;
      int nb = mb & 1023;  // token index; nb ≡ g4 (mod 16)
#pragma unroll
      for (int nt = 0; nt < 4; ++nt) {
        int c = n0 + wn * 64 + nt * 16 + li;
        int cs = c & 511;
        int hh = cs >> 6, d = cs & 63;
        size_t bhoff = (size_t)(b_ * Hh + hh) * 65536;
        if (sec == 2) {
          int dt = d >> 4, liD = d & 15;
          int kkJ = (nb >> 5) & 1;
          int gj = (nb & 15) >> 2;
          int s0 = (nb & 16) >> 2;  // 0 or 4
          size_t off = bhoff + (size_t)(nb >> 6) * 4096 +
                       (size_t)((dt * 2 + kkJ) * 512) + (size_t)(liD + 16 * gj) * 8 + s0;
          uint2 st;
          st.x = cvtpk(acc[mt][nt][0], acc[mt][nt][1]);
          st.y = cvtpk(acc[mt][nt][2], acc[mt][nt][3]);
          *(uint2*)(vt + off) = st;
        } else {
          int kkD = d >> 5;
          int gd = (d & 15) >> 2;
          int sD = (d & 3) | ((d & 16) >> 2);
          size_t off = bhoff + (size_t)(nb >> 4) * 1024 + (size_t)(kkD * 512) +
                       (size_t)((nb & 15) + 16 * gd) * 8 + sD;
          short* dst = (sec == 0 ? qr : kr) + off;
#pragma unroll
          for (int r = 0; r < 4; ++r) {
            float v0 = acc[mt][nt][r];
            float vp = __shfl_xor(v0, 1, 64);  // RoPE pair partner (adjacent d)
            float2 cssn = tab[(size_t)(nb + r) * 32 + (d >> 1)];
            float rot = (d & 1) ? vp : -vp;
            float res = v0 * cssn.x + rot * cssn.y;
            if (sec == 0) res *= 0.125f;  // Dh^-0.5 (e-domain; LOG2E applied in exp)
            dst[(size_t)r * 8] = f2bf(res);
          }
        }
      }
    }
  }
}

// ---------------------------------------------------------------------------
// Flash attention v9 = v6 shell + LDS-staged bf16 bias.
// Per tile (KVBLK=64): STAGE(next: K 8KB + V 8KB + bias-bf16 8KB via
// global_load_lds) -> compute current -> vmcnt(0)+barrier.
// Bias LDS tile [64 q-rows][64 j] bf16 with XOR-swizzled chunks
// (both-sides involution: source chunk (c*16)^((r&7)<<4), read addr
// (js*32+q8)^((li&7)<<4)) -> 2-way max bank aliasing (free).
// LDS 48KB/block -> 3 blocks/CU, 12 waves/CU.
// ---------------------------------------------------------------------------
constexpr int KVB = 64;
constexpr int NTT = Nn / KVB;  // 16

__global__ __launch_bounds__(256, 3) void attn_k(const short* __restrict__ qf_g,
                                                 const short* __restrict__ kf_g,
                                                 const short* __restrict__ vf_g,
                                                 const short* __restrict__ bias_bf,
                                                 short* __restrict__ ao) {
  __shared__ short Kls[2][4096];  // [buf][64j x 64d frag-order], 8 KB each
  __shared__ short Vls[2][4096];  // [buf][64d x 64j frag-order], 8 KB each
  __shared__ short Bls[2][4096];  // [buf][64 q-rows x 64 j bf16, swizzled], 8 KB
  const int tid = threadIdx.x, lane = tid & 63, w = tid >> 6;
  const int li = lane & 15, g4 = (lane >> 4) << 2;
  // Block mapping: h pin to XCD, b_ fast (bias L2 reuse across batch), it slow.
  const int bid = blockIdx.x;
  const int h = bid & 7;
  const int b_ = (bid >> 3) & 7;
  const int it = bid >> 6;
  const int bh = b_ * 8 + h;
  const int i0 = it * 64;

  const short* qbase = qf_g + (size_t)bh * 65536 + (size_t)(it * 4 + w) * 1024 + lane * 8;
  bf16x8 qf0 = *(const bf16x8*)(qbase);
  bf16x8 qf1 = *(const bf16x8*)(qbase + 512);

  const short* kb = kf_g + (size_t)bh * 65536;
  const short* vb = vf_g + (size_t)bh * 65536;

  // bias staging source (per-lane, swizzled chunks; rule-21 involution)
  const int brow = tid >> 3;    // 0..31 (second chunk: +32)
  const int bchunk = tid & 7;   // 16B chunk within 128B row
  const char* bsrc0 = (const char*)bias_bf + ((size_t)h << 21) +
                      (size_t)(i0 + brow) * 2048 +
                      (size_t)((bchunk * 16) ^ ((brow & 7) << 4));
  const char* bsrc1 = bsrc0 + (size_t)32 * 2048;  // (brow+32)&7 == brow&7

  // bias read-side swizzle constants
  const int q8 = (lane >> 4) << 3;   // byte offset of g4 within a 32B js-half
  const int bswz = (li & 7) << 4;
  const int brd_row = (w * 16 + li) * 128;  // this lane's q-row base (bytes)

  float m_run = -1e30f, l_run = 0.f;
  f32x4 zero4 = {0.f, 0.f, 0.f, 0.f};
  f32x4 acc[4];
#pragma unroll
  for (int i = 0; i < 4; ++i) acc[i] = zero4;

  // ---- staging: K 8KB + V 8KB + bias 8KB per tile (6 gload16/thread) ----
#define STAGE_TILE(T, BUF)                                                  \
  do {                                                                      \
    const short* ks_ = kb + (size_t)(T) * 4096;                             \
    const short* vs_ = vb + (size_t)(T) * 4096;                             \
    gload16(ks_ + (size_t)tid * 8, &Kls[BUF][(size_t)(w * 64) * 8]);        \
    gload16(ks_ + (size_t)(256 + tid) * 8,                                  \
            &Kls[BUF][(size_t)(256 + w * 64) * 8]);                         \
    gload16(vs_ + (size_t)tid * 8, &Vls[BUF][(size_t)(w * 64) * 8]);        \
    gload16(vs_ + (size_t)(256 + tid) * 8,                                  \
            &Vls[BUF][(size_t)(256 + w * 64) * 8]);                         \
    gload16(bsrc0 + (size_t)(T) * 128, &Bls[BUF][(size_t)(w * 64) * 8]);    \
    gload16(bsrc1 + (size_t)(T) * 128,                                      \
            &Bls[BUF][(size_t)(256 + w * 64) * 8]);                         \
  } while (0)

  // prologue: stage tile 0
  STAGE_TILE(0, 0);
  asm volatile("s_waitcnt vmcnt(0)" ::: "memory");
  __builtin_amdgcn_s_barrier();

  int cur = 0;
#pragma unroll 1
  for (int t = 0; t < NTT; ++t) {
    // phase 1: issue next tile's staging (stays in flight across compute)
    if (t + 1 < NTT) STAGE_TILE(t + 1, cur ^ 1);

    // phase 2: compute current tile from LDS
    const short* KB = &Kls[cur][0];
    const short* VB = &Vls[cur][0];
    const char* BP = (const char*)&Bls[cur][0] + brd_row;
    f32x4 s[4];
    __builtin_amdgcn_s_setprio(1);
#pragma unroll
    for (int js = 0; js < 4; ++js) {
      // bias C-init: swizzled ds_read_b64, expand bf16 -> f32
      uint2 bd = *(const uint2*)(BP + ((js * 32 + q8) ^ bswz));
      f32x4 bb;
      bb[0] = __uint_as_float(bd.x << 16);
      bb[1] = __uint_as_float(bd.x & 0xffff0000u);
      bb[2] = __uint_as_float(bd.y << 16);
      bb[3] = __uint_as_float(bd.y & 0xffff0000u);
      bf16x8 k0 = *(const bf16x8*)(KB + js * 1024 + lane * 8);
      bf16x8 k1 = *(const bf16x8*)(KB + js * 1024 + 512 + lane * 8);
      f32x4 sa = mfma16(k0, qf0, bb);
      s[js] = mfma16(k1, qf1, sa);
    }
    __builtin_amdgcn_s_setprio(0);

    // row max
    float mx = fmaxf(fmaxf(fmaxf(s[0][0], s[0][1]), fmaxf(s[0][2], s[0][3])),
                     fmaxf(fmaxf(s[1][0], s[1][1]), fmaxf(s[1][2], s[1][3])));
    float mx2 = fmaxf(fmaxf(fmaxf(s[2][0], s[2][1]), fmaxf(s[2][2], s[2][3])),
                      fmaxf(fmaxf(s[3][0], s[3][1]), fmaxf(s[3][2], s[3][3])));
    mx = fmaxf(mx, mx2);
    mx = fmaxf(mx, __shfl_xor(mx, 16, 64));
    mx = fmaxf(mx, __shfl_xor(mx, 32, 64));

    if (!__all(mx - m_run <= 8.0f)) {  // defer-max (T13)
      float mn = fmaxf(m_run, mx);
      float sc = __builtin_amdgcn_exp2f((m_run - mn) * LOG2E);
      l_run *= sc;
      m_run = mn;
      float fs0 = __shfl(sc, g4 + 0, 64), fs1 = __shfl(sc, g4 + 1, 64);
      float fs2 = __shfl(sc, g4 + 2, 64), fs3 = __shfl(sc, g4 + 3, 64);
#pragma unroll
      for (int dt = 0; dt < 4; ++dt) {
        acc[dt][0] *= fs0; acc[dt][1] *= fs1;
        acc[dt][2] *= fs2; acc[dt][3] *= fs3;
      }
    }

    float nm = -m_run * LOG2E;
    float rs = 0.f;
#pragma unroll
    for (int js = 0; js < 4; ++js)
#pragma unroll
      for (int r = 0; r < 4; ++r) {
        float p = __builtin_amdgcn_exp2f(__builtin_fmaf(s[js][r], LOG2E, nm));
        s[js][r] = p;
        rs += p;
      }
    rs += __shfl_xor(rs, 16, 64);
    rs += __shfl_xor(rs, 32, 64);
    l_run += rs;

    // P -> bf16 A-frags: pf[kk] covers j in [32kk, 32kk+32)
    bf16x8 pf[2];
#pragma unroll
    for (int kk = 0; kk < 2; ++kk) {
      union { bf16x8 v8; unsigned int d[4]; } u;
      u.d[0] = cvtpk(s[2 * kk][0], s[2 * kk][1]);
      u.d[1] = cvtpk(s[2 * kk][2], s[2 * kk][3]);
      u.d[2] = cvtpk(s[2 * kk + 1][0], s[2 * kk + 1][1]);
      u.d[3] = cvtpk(s[2 * kk + 1][2], s[2 * kk + 1][3]);
      pf[kk] = u.v8;
    }

    // PV
    __builtin_amdgcn_s_setprio(1);
#pragma unroll
    for (int dt = 0; dt < 4; ++dt) {
      bf16x8 vf0 = *(const bf16x8*)(VB + (dt * 2 + 0) * 512 + lane * 8);
      bf16x8 vf1 = *(const bf16x8*)(VB + (dt * 2 + 1) * 512 + lane * 8);
      f32x4 a = mfma16(pf[0], vf0, acc[dt]);
      acc[dt] = mfma16(pf[1], vf1, a);
    }
    __builtin_amdgcn_s_setprio(0);

    // phase 3: next tile's staging is done by now; sync buffers
    asm volatile("s_waitcnt vmcnt(0)" ::: "memory");
    __builtin_amdgcn_s_barrier();
    cur ^= 1;
  }
#undef STAGE_TILE

  float rl = 1.f / l_run;
  float fr0 = __shfl(rl, g4 + 0, 64), fr1 = __shfl(rl, g4 + 1, 64);
  float fr2 = __shfl(rl, g4 + 2, 64), fr3 = __shfl(rl, g4 + 3, 64);
#pragma unroll
  for (int dt = 0; dt < 4; ++dt) {
    float fr[4] = {fr0, fr1, fr2, fr3};
#pragma unroll
    for (int r = 0; r < 4; ++r) {
      int i_ = i0 + w * 16 + g4 + r;
      ao[((size_t)(b_ * Nn + i_)) * 512 + h * 64 + dt * 16 + li] =
          f2bf(acc[dt][r] * fr[r]);
    }
  }
}

// ---------------------------------------------------------------------------
extern "C" void kernel_launch(void* const* d_in, const int* in_sizes, int n_in,
                              void* d_out, int out_size, void* d_ws, size_t ws_size,
                              hipStream_t stream) {
  const float* x = (const float*)d_in[0];
  const float* pb = (const float*)d_in[1];
  const float* wq = (const float*)d_in[2];
  const float* wo = (const float*)d_in[3];
  float* out = (float*)d_out;

  short* w = (short*)d_ws;
  short* x_bf = w;  w += (size_t)Mm * DIMm;      // 8 MB
  short* wqkvT = w; w += 1536 * 512;             // 1.5 MB
  short* woutT = w; w += 512 * 512;              // 0.5 MB
  short* qr = w;    w += (size_t)Mm * DIMm;      // 8 MB (frag-order)
  short* kr = w;    w += (size_t)Mm * DIMm;      // 8 MB (frag-order)
  short* vt = w;    w += (size_t)Mm * DIMm;      // 8 MB (frag-order)
  float2* tab = (float2*)w; w += Nn * 32 * 4;    // 256 KB
  short* bias_bf = w; w += (size_t)Hh * Nn * Nn; // 16 MB (bf16, row-order)
  short* ao = x_bf;  // x_bf dead after qkv GEMM

  prep_kernel<<<1024, 256, 0, stream>>>(x, wq, wo, x_bf, wqkvT, woutT, tab);
  gemm_k<1><<<dim3(64, 12), 256, 0, stream>>>(x_bf, wqkvT, nullptr, qr, kr, vt, tab);
  bias_cvt<<<2048, 256, 0, stream>>>(pb, bias_bf);
  attn_k<<<1024, 256, 0, stream>>>(qr, kr, vt, bias_bf, ao);
  gemm_k<0><<<dim3(64, 4), 256, 0, stream>>>(ao, woutT, out, nullptr, nullptr, nullptr, tab);
}